// Round 18
// baseline (130.185 us; speedup 1.0000x reference)
//
#include <hip/hip_runtime.h>

// ---------- types ----------
typedef __bf16 bf16x8 __attribute__((ext_vector_type(8)));
typedef float f32x4 __attribute__((ext_vector_type(4)));
typedef float f32x16 __attribute__((ext_vector_type(16)));
typedef unsigned short u16x8 __attribute__((ext_vector_type(8)));
typedef unsigned short u16x4 __attribute__((ext_vector_type(4)));
typedef unsigned int u32x2 __attribute__((ext_vector_type(2)));

__device__ __forceinline__ unsigned short f2bf(float f) {
  union { float f; unsigned int u; } v; v.f = f;
  unsigned int r = v.u + 0x7FFFu + ((v.u >> 16) & 1u);
  return (unsigned short)(r >> 16);
}
__device__ __forceinline__ unsigned short bfbits(float f) {
  union { __bf16 b; unsigned short u; } c; c.b = (__bf16)f; return c.u;
}

// global -> LDS direct copy, 16B per lane; lds dst is wave-uniform base (+lane*16 by HW)
__device__ __forceinline__ void gload_lds16(const void* g, void* l) {
  __builtin_amdgcn_global_load_lds(
      (const __attribute__((address_space(1))) void*)g,
      (__attribute__((address_space(3))) void*)l, 16, 0, 0);
}

// ---------- prep: conv (blocks 0..4095) + weight cvt (blocks 4096..8191) ----------
__global__ __launch_bounds__(256)
void prep_kernel(const float* __restrict__ x,
                 const float* __restrict__ wq3, const float* __restrict__ bq3,
                 const float* __restrict__ wk3, const float* __restrict__ bk3,
                 const float* __restrict__ wv3, const float* __restrict__ bv3,
                 unsigned short* __restrict__ cq, unsigned short* __restrict__ ck,
                 unsigned short* __restrict__ cv,
                 const float* __restrict__ wq, const float* __restrict__ wk,
                 const float* __restrict__ wv, const float* __restrict__ wo,
                 unsigned short* __restrict__ wqb, unsigned short* __restrict__ wkb,
                 unsigned short* __restrict__ wvb, unsigned short* __restrict__ wob)
{
  if (blockIdx.x >= 4096) {
    int bb = blockIdx.x - 4096;
    const float* src; unsigned short* dst;
    switch (bb >> 10) {
      case 0: src = wq; dst = wqb; break;
      case 1: src = wk; dst = wkb; break;
      case 2: src = wv; dst = wvb; break;
      default: src = wo; dst = wob; break;
    }
    int i = (bb & 1023) * 1024 + threadIdx.x * 4;
    f32x4 v = *(const f32x4*)(src + i);
    u16x4 o;
    #pragma unroll
    for (int j = 0; j < 4; j++) o[j] = f2bf(v[j]);
    *(u16x4*)(dst + i) = o;
    return;
  }
  int t = blockIdx.x;            // b*2048+s, 0..4095
  int s = t & 2047;
  int d0 = threadIdx.x * 4;
  int base = t * 1024 + d0;
  f32x4 xc = *(const f32x4*)(x + base);
  f32x4 xm = (s > 0)    ? *(const f32x4*)(x + base - 1024) : f32x4{0.f,0.f,0.f,0.f};
  f32x4 xp = (s < 2047) ? *(const f32x4*)(x + base + 1024) : f32x4{0.f,0.f,0.f,0.f};

  #pragma unroll
  for (int path = 0; path < 3; path++) {
    const float* wP = (path == 0) ? wq3 : ((path == 1) ? wk3 : wv3);
    const float* bP = (path == 0) ? bq3 : ((path == 1) ? bk3 : bv3);
    unsigned short* oP = (path == 0) ? cq : ((path == 1) ? ck : cv);
    f32x4 w0 = *(const f32x4*)(wP + d0*3);
    f32x4 w1 = *(const f32x4*)(wP + d0*3 + 4);
    f32x4 w2 = *(const f32x4*)(wP + d0*3 + 8);
    f32x4 b4 = *(const f32x4*)(bP + d0);
    u16x4 o;
    #pragma unroll
    for (int dd = 0; dd < 4; dd++) {
      float wa, wb, wc;
      int j0 = dd*3, j1 = dd*3+1, j2 = dd*3+2;
      wa = (j0 < 4) ? w0[j0] : ((j0 < 8) ? w1[j0-4] : w2[j0-8]);
      wb = (j1 < 4) ? w0[j1] : ((j1 < 8) ? w1[j1-4] : w2[j1-8]);
      wc = (j2 < 4) ? w0[j2] : ((j2 < 8) ? w1[j2-4] : w2[j2-8]);
      o[dd] = f2bf(xm[dd]*wa + xc[dd]*wb + xp[dd]*wc + b4[dd]);
    }
    *(u16x4*)(oP + base) = o;
  }
}

// ---------- q/k/v projections; BK=32, 3-buffer, counted vmcnt, 1 barrier/iter ----------
// q/k -> [B,H,S,64]; v -> tile-blocked [bh][S/64][64d][64k]
__global__ __launch_bounds__(256, 3)
void gemm_qkv_kernel(const unsigned short* __restrict__ cq, const unsigned short* __restrict__ ck,
                     const unsigned short* __restrict__ cv,
                     const unsigned short* __restrict__ wqb, const unsigned short* __restrict__ wkb,
                     const unsigned short* __restrict__ wvb,
                     const float* __restrict__ bq, const float* __restrict__ bk,
                     const float* __restrict__ bv,
                     unsigned short* __restrict__ qo, unsigned short* __restrict__ ko,
                     unsigned short* __restrict__ vtb)
{
  const int K = 1024;
  __shared__ alignas(16) unsigned short lA[3 * 4096];   // 128x32 per buf
  __shared__ alignas(16) unsigned short lB[3 * 4096];
  int z = blockIdx.z;
  const unsigned short* A = (z == 0) ? cq : ((z == 1) ? ck : cv);
  const unsigned short* W = (z == 0) ? wqb : ((z == 1) ? wkb : wvb);
  const float* bias       = (z == 0) ? bq : ((z == 1) ? bk : bv);
  // Q: fold 1/sqrt(64) AND log2(e) so attn can use exp2 with no per-element fixup
  float scale             = (z == 0) ? 0.125f * 1.4426950408889634f : 1.0f;

  int bm = blockIdx.y * 128, bn = blockIdx.x * 128;
  const int tid = threadIdx.x, lane = tid & 63, w = tid >> 6;
  const int lrow = lane & 15, lgrp = lane >> 4;
  const int wm = (w >> 1) * 64, wn = (w & 1) * 64;

  f32x4 acc[4][4];
  #pragma unroll
  for (int i = 0; i < 4; i++)
    #pragma unroll
    for (int j = 0; j < 4; j++) acc[i][j] = f32x4{0.f,0.f,0.f,0.f};

  // LDS[row][c] = global[row][c ^ (row&3)] (involution): linear dest, swizzled source
  auto STAGE = [&](int buf, int k0) {
    #pragma unroll
    for (int c = 0; c < 2; c++) {
      int slot_base = c * 256 + w * 64;          // wave-uniform
      int slot = slot_base + lane;
      int row = slot >> 2;
      int kc8 = ((slot & 3) ^ (row & 3)) << 3;
      gload_lds16(A + (size_t)(bm + row) * K + k0 + kc8, lA + buf * 4096 + slot_base * 8);
      gload_lds16(W + (size_t)(bn + row) * K + k0 + kc8, lB + buf * 4096 + slot_base * 8);
    }
  };

  STAGE(0, 0);
  STAGE(1, 32);
  int cur = 0, stg = 2;

  for (int t = 0; t < 32; t++) {
    if (t < 31) { asm volatile("s_waitcnt vmcnt(4)" ::: "memory"); }
    else        { asm volatile("s_waitcnt vmcnt(0)" ::: "memory"); }
    __builtin_amdgcn_s_barrier();
    __builtin_amdgcn_sched_barrier(0);
    if (t + 2 < 32) STAGE(stg, (t + 2) * 32);

    bf16x8 af[4], bfr[4];
    #pragma unroll
    for (int mt = 0; mt < 4; mt++) {
      int rr = wm + mt*16 + lrow;
      af[mt] = *(const bf16x8*)(lA + cur*4096 + (rr << 5) + ((lgrp ^ (rr & 3)) << 3));
    }
    #pragma unroll
    for (int nt = 0; nt < 4; nt++) {
      int rr = wn + nt*16 + lrow;
      bfr[nt] = *(const bf16x8*)(lB + cur*4096 + (rr << 5) + ((lgrp ^ (rr & 3)) << 3));
    }
    #pragma unroll
    for (int mt = 0; mt < 4; mt++)
      #pragma unroll
      for (int nt = 0; nt < 4; nt++)
        acc[mt][nt] = __builtin_amdgcn_mfma_f32_16x16x32_bf16(af[mt], bfr[nt], acc[mt][nt], 0, 0, 0);

    cur = (cur == 2) ? 0 : cur + 1;
    stg = (stg == 2) ? 0 : stg + 1;
  }

  if (z == 2) {
    // V: write transposed tile-blocked [tile][64d][64k]; i=0..3 consecutive s -> inner k
    #pragma unroll
    for (int mt = 0; mt < 4; mt++) {
      #pragma unroll
      for (int nt = 0; nt < 4; nt++) {
        int gn = bn + wn + nt*16 + lrow;
        float bb = bias[gn];
        int h = gn >> 6, dk = gn & 63;
        int gm0 = bm + wm + mt*16 + lgrp*4;
        int b = gm0 >> 11, s0 = gm0 & 2047;
        u16x4 pk;
        #pragma unroll
        for (int i = 0; i < 4; i++) pk[i] = f2bf(acc[mt][nt][i] + bb);
        unsigned short* dst = vtb +
            ((((size_t)(b*16 + h)) * 32 + (s0 >> 6)) * 64 + dk) * 64 + (s0 & 63);
        *(u16x4*)dst = pk;
      }
    }
  } else {
    unsigned short* O = (z == 0) ? qo : ko;
    #pragma unroll
    for (int mt = 0; mt < 4; mt++) {
      #pragma unroll
      for (int nt = 0; nt < 4; nt++) {
        int gn = bn + wn + nt*16 + lrow;
        float bb = bias[gn];
        int h = gn >> 6, dk = gn & 63;
        #pragma unroll
        for (int i = 0; i < 4; i++) {
          int gm = bm + wm + mt*16 + lgrp*4 + i;     // b*2048+s
          int b = gm >> 11, s = gm & 2047;
          float val = (acc[mt][nt][i] + bb) * scale;
          O[((size_t)(b*16 + h) * 2048 + s) * 64 + dk] = f2bf(val);
        }
      }
    }
  }
}

// ---------- final projection: f32 out; 64x128 tiles, BK=32, 3-buffer counted ----------
__global__ __launch_bounds__(256)
void gemm_out_kernel(const unsigned short* __restrict__ A, const unsigned short* __restrict__ W,
                     const float* __restrict__ bias, float* __restrict__ Out)
{
  const int K = 1024;
  __shared__ alignas(16) unsigned short lA[3 * 2048];   // 64x32 per buf
  __shared__ alignas(16) unsigned short lB[3 * 4096];   // 128x32 per buf
  int bm = blockIdx.y * 64, bn = blockIdx.x * 128;
  const int tid = threadIdx.x, lane = tid & 63, w = tid >> 6;
  const int lrow = lane & 15, lgrp = lane >> 4;
  const int wm = (w >> 1) * 32, wn = (w & 1) * 64;

  f32x4 acc[2][4];
  #pragma unroll
  for (int mt = 0; mt < 2; mt++)
    #pragma unroll
    for (int nt = 0; nt < 4; nt++) acc[mt][nt] = f32x4{0.f,0.f,0.f,0.f};

  auto STAGE = [&](int buf, int k0) {
    {
      int slot = tid;                          // 256 slots for A
      int row = slot >> 2;
      int kc8 = ((slot & 3) ^ (row & 3)) << 3;
      gload_lds16(A + (size_t)(bm + row) * K + k0 + kc8, lA + buf * 2048 + (w * 64) * 8);
    }
    #pragma unroll
    for (int c = 0; c < 2; c++) {
      int slot_base = c * 256 + w * 64;
      int slot = slot_base + lane;
      int row = slot >> 2;
      int kc8 = ((slot & 3) ^ (row & 3)) << 3;
      gload_lds16(W + (size_t)(bn + row) * K + k0 + kc8, lB + buf * 4096 + slot_base * 8);
    }
  };

  STAGE(0, 0);
  STAGE(1, 32);
  int cur = 0, stg = 2;

  for (int t = 0; t < 32; t++) {
    if (t < 31) { asm volatile("s_waitcnt vmcnt(3)" ::: "memory"); }
    else        { asm volatile("s_waitcnt vmcnt(0)" ::: "memory"); }
    __builtin_amdgcn_s_barrier();
    __builtin_amdgcn_sched_barrier(0);
    if (t + 2 < 32) STAGE(stg, (t + 2) * 32);

    bf16x8 af[2], bfr[4];
    #pragma unroll
    for (int mt = 0; mt < 2; mt++) {
      int rr = wm + mt*16 + lrow;
      af[mt] = *(const bf16x8*)(lA + cur*2048 + (rr << 5) + ((lgrp ^ (rr & 3)) << 3));
    }
    #pragma unroll
    for (int nt = 0; nt < 4; nt++) {
      int rr = wn + nt*16 + lrow;
      bfr[nt] = *(const bf16x8*)(lB + cur*4096 + (rr << 5) + ((lgrp ^ (rr & 3)) << 3));
    }
    #pragma unroll
    for (int mt = 0; mt < 2; mt++)
      #pragma unroll
      for (int nt = 0; nt < 4; nt++)
        acc[mt][nt] = __builtin_amdgcn_mfma_f32_16x16x32_bf16(af[mt], bfr[nt], acc[mt][nt], 0, 0, 0);

    cur = (cur == 2) ? 0 : cur + 1;
    stg = (stg == 2) ? 0 : stg + 1;
  }

  #pragma unroll
  for (int mt = 0; mt < 2; mt++) {
    #pragma unroll
    for (int nt = 0; nt < 4; nt++) {
      int gn = bn + wn + nt*16 + lrow;
      float bb = bias[gn];
      #pragma unroll
      for (int i = 0; i < 4; i++) {
        int gm = bm + wm + mt*16 + lgrp*4 + i;
        Out[(size_t)gm * 1024 + gn] = acc[mt][nt][i] + bb;
      }
    }
  }
}

// ---------- flash attention: swapped QK^T + in-reg P; 128-key double tiles ----------
// 4 waves x 32 q; grid 512. LDS 64KB: 2-buf x (16KB K + 16KB V), XOR-swizzled staging.
// NT=16 iterations of 128 keys (r17). Softmax: P = exp2(s') (log2e folded into Q),
// l on VALU. CHANGE vs r17 (m240): P-packing via native (__bf16) casts + shift-or
// (compiler schedules/fuses) instead of 32 inline-asm v_cvt_pk_bf16_f32 per iter;
// permlane32_swap builtins unchanged.
__global__ __launch_bounds__(256, 2)
void attn_kernel(const unsigned short* __restrict__ Q, const unsigned short* __restrict__ K,
                 const unsigned short* __restrict__ Vtb, unsigned short* __restrict__ O)
{
  const int S = 2048, NT = 16;          // 128-key tiles
  int n = blockIdx.x;
  int xcd = n & 7, r = n >> 3;          // r: 0..63
  int bh = (xcd << 2) | (r & 3);
  int qbase = (r >> 2) * 128;

  const int tid = threadIdx.x, lane = tid & 63, w = tid >> 6;   // 4 waves
  const int lq = lane & 31;             // q-col / key-row / d-row within 32
  const int lh = lane >> 5;             // half 0/1
  const unsigned short* Qh = Q   + (size_t)bh * S * 64;
  const unsigned short* Kh = K   + (size_t)bh * S * 64;
  const unsigned short* Vh = Vtb + (size_t)bh * 32 * 4096;   // [tile64][64d][64k], contiguous

  __shared__ alignas(16) unsigned short Kb[2][8192];   // 128 rows x 64, XOR swizzle
  __shared__ alignas(16) unsigned short Vb[2][8192];   // 2 consecutive vtb tiles

  bf16x8 qf[4];
  {
    const unsigned short* qp = Qh + (size_t)(qbase + w*32 + lq) * 64 + lh * 8;
    #pragma unroll
    for (int ks = 0; ks < 4; ks++)
      qf[ks] = *(const bf16x8*)(qp + ks * 16);
  }

  f32x16 oacc[2];
  #pragma unroll
  for (int i = 0; i < 16; i++) { oacc[0][i] = 0.f; oacc[1][i] = 0.f; }
  float lsum = 0.f;   // partial row-sum for q = qbase + w*32 + lq (this lane's half)

  // staging: 16KB per matrix = 1024 chunks; 256 thr -> 4 each (8 instr/wave total).
  // LDS[row][c] = global[row][c ^ (row&7)] (involution; linear dest, swizzled source)
  auto STAGE = [&](int buf, int gt) {
    const unsigned short* gK = Kh + (size_t)gt * 8192;
    const unsigned short* gV = Vh + (size_t)gt * 8192;   // vtb tiles 2gt,2gt+1 contiguous
    #pragma unroll
    for (int c = 0; c < 4; c++) {
      int slot_base = c * 256 + w * 64;          // wave-uniform
      int slot = slot_base + lane;
      int row = slot >> 3;                       // 0..127
      int srcoff = (row << 6) + (((slot & 7) ^ (row & 7)) << 3);
      gload_lds16(gK + srcoff, &Kb[buf][slot_base * 8]);
      gload_lds16(gV + srcoff, &Vb[buf][slot_base * 8]);
    }
  };

  STAGE(0, 0);
  int cur = 0;

  for (int t = 0; t < NT; t++) {
    asm volatile("s_waitcnt vmcnt(0)" ::: "memory");   // tile t landed (issued 1 iter ago)
    __builtin_amdgcn_s_barrier();
    __builtin_amdgcn_sched_barrier(0);
    if (t + 1 < NT) STAGE(cur ^ 1, t + 1);

    // ---- S^T = K Q^T : 16 MFMA over 4 key-subtiles of 32 ----
    f32x16 sacc[4];
    #pragma unroll
    for (int kt = 0; kt < 4; kt++)
      #pragma unroll
      for (int i = 0; i < 16; i++) sacc[kt][i] = 0.f;
    #pragma unroll
    for (int ks = 0; ks < 4; ks++) {
      #pragma unroll
      for (int kt = 0; kt < 4; kt++) {
        int row = kt*32 + lq;                     // key-row 0..127
        bf16x8 kf = *(const bf16x8*)(&Kb[cur][(row << 6) + ((((ks<<1)+lh) ^ (row & 7)) << 3)]);
        sacc[kt] = __builtin_amdgcn_mfma_f32_32x32x16_bf16(kf, qf[ks], sacc[kt], 0, 0, 0);
      }
    }

    // ---- P = exp2(s'); l-sum; native-cast pack + permlane32_swap -> 8 A-frags ----
    bf16x8 pa[8];
    #pragma unroll
    for (int kp = 0; kp < 8; kp++) {
      const int sv = kp >> 1;        // sacc subtile
      const int rb = (kp & 1) * 8;   // reg base
      float p[8];
      #pragma unroll
      for (int i = 0; i < 8; i++)
        p[i] = __builtin_amdgcn_exp2f(sacc[sv][rb + i]);
      lsum += ((p[0]+p[1]) + (p[2]+p[3])) + ((p[4]+p[5]) + (p[6]+p[7]));
      unsigned int X  = (unsigned int)bfbits(p[0]) | ((unsigned int)bfbits(p[1]) << 16);
      unsigned int Y  = (unsigned int)bfbits(p[2]) | ((unsigned int)bfbits(p[3]) << 16);
      unsigned int Z  = (unsigned int)bfbits(p[4]) | ((unsigned int)bfbits(p[5]) << 16);
      unsigned int W2 = (unsigned int)bfbits(p[6]) | ((unsigned int)bfbits(p[7]) << 16);
      u32x2 rxz = __builtin_amdgcn_permlane32_swap(X, Z, false, false);
      u32x2 ryw = __builtin_amdgcn_permlane32_swap(Y, W2, false, false);
      union { unsigned int u[4]; bf16x8 v; } pk;
      pk.u[0] = rxz[0]; pk.u[1] = ryw[0]; pk.u[2] = rxz[1]; pk.u[3] = ryw[1];
      pa[kp] = pk.v;
    }

    // ---- O^T += (P V)^T : 16 MFMA; V rows 0..63 = keys 0..63, rows 64..127 = keys 64..127 ----
    __builtin_amdgcn_s_setprio(1);
    #pragma unroll
    for (int kp = 0; kp < 8; kp++) {
      int rbase = (kp >> 2) << 6;                 // 0 or 64 (which vtb tile)
      int ck = ((kp & 3) << 1) + lh;              // k-chunk within tile
      #pragma unroll
      for (int dt = 0; dt < 2; dt++) {
        int row = rbase + dt*32 + lq;
        bf16x8 vf = *(const bf16x8*)(&Vb[cur][(row << 6) + ((ck ^ (row & 7)) << 3)]);
        oacc[dt] = __builtin_amdgcn_mfma_f32_32x32x16_bf16(pa[kp], vf, oacc[dt], 0, 0, 0);
      }
    }
    __builtin_amdgcn_s_setprio(0);

    cur ^= 1;
  }

  // l(q): combine halves once (lane lq,lh held keys of its half for q = w*32+lq)
  float ltot = lsum + __shfl_xor(lsum, 32, 64);

  // epilogue: D layout col=lane&31 -> d, row=(reg&3)+8*(reg>>2)+4*lh -> q.
  int b = bh >> 4, h = bh & 15;
  #pragma unroll
  for (int reg = 0; reg < 16; reg++) {
    int qrl = (reg & 3) + 8*(reg >> 2) + 4*lh;     // 0..31
    float lq_ = __shfl(ltot, qrl, 64);
    float rl = 1.0f / lq_;
    int qrow = qbase + w*32 + qrl;
    unsigned short* dst = O + ((size_t)(b*2048 + qrow)) * 1024 + h*64 + lq;
    dst[0]  = f2bf(oacc[0][reg] * rl);
    dst[32] = f2bf(oacc[1][reg] * rl);
  }
}

// ---------- launcher ----------
extern "C" void kernel_launch(void* const* d_in, const int* in_sizes, int n_in,
                              void* d_out, int out_size, void* d_ws, size_t ws_size,
                              hipStream_t stream)
{
  const float* x     = (const float*)d_in[0];
  const float* dwq_w = (const float*)d_in[1];
  const float* dwq_b = (const float*)d_in[2];
  const float* dwk_w = (const float*)d_in[3];
  const float* dwk_b = (const float*)d_in[4];
  const float* dwv_w = (const float*)d_in[5];
  const float* dwv_b = (const float*)d_in[6];
  const float* wq    = (const float*)d_in[7];
  const float* bq    = (const float*)d_in[8];
  const float* wk    = (const float*)d_in[9];
  const float* bk    = (const float*)d_in[10];
  const float* wv    = (const float*)d_in[11];
  const float* bv    = (const float*)d_in[12];
  const float* wo    = (const float*)d_in[13];
  const float* bo    = (const float*)d_in[14];
  float* out = (float*)d_out;

  char* ws = (char*)d_ws;
  const size_t MB = 1024 * 1024;
  unsigned short* cq  = (unsigned short*)(ws + 0);        // 8MB (reused as attn_out)
  unsigned short* ck  = (unsigned short*)(ws + 8*MB);     // 8MB (reused as vtb)
  unsigned short* cv  = (unsigned short*)(ws + 16*MB);
  unsigned short* qd  = (unsigned short*)(ws + 24*MB);    // [B,H,S,64] bf16
  unsigned short* kd  = (unsigned short*)(ws + 32*MB);
  unsigned short* wqb = (unsigned short*)(ws + 48*MB);
  unsigned short* wkb = (unsigned short*)(ws + 50*MB);
  unsigned short* wvb = (unsigned short*)(ws + 52*MB);
  unsigned short* wob = (unsigned short*)(ws + 54*MB);
  unsigned short* attn_out = cq;                          // cq dead after gemm_qkv
  unsigned short* vtb      = ck;                          // ck dead after gemm_qkv

  prep_kernel<<<8192, 256, 0, stream>>>(x, dwq_w, dwq_b, dwk_w, dwk_b, dwv_w, dwv_b,
                                        cq, ck, cv, wq, wk, wv, wo, wqb, wkb, wvb, wob);
  gemm_qkv_kernel<<<dim3(8, 32, 3), 256, 0, stream>>>(cq, ck, cv, wqb, wkb, wvb, bq, bk, bv, qd, kd, vtb);
  attn_kernel<<<512, 256, 0, stream>>>(qd, kd, vtb, attn_out);
  gemm_out_kernel<<<dim3(8, 64), 256, 0, stream>>>(attn_out, wob, bo, out);
}

// Round 19
// 125.980 us; speedup vs baseline: 1.0334x; 1.0334x over previous
//
#include <hip/hip_runtime.h>

// ---------- types ----------
typedef __bf16 bf16x8 __attribute__((ext_vector_type(8)));
typedef float f32x4 __attribute__((ext_vector_type(4)));
typedef float f32x16 __attribute__((ext_vector_type(16)));
typedef unsigned short u16x8 __attribute__((ext_vector_type(8)));
typedef unsigned short u16x4 __attribute__((ext_vector_type(4)));
typedef unsigned int u32x2 __attribute__((ext_vector_type(2)));

__device__ __forceinline__ unsigned short f2bf(float f) {
  union { float f; unsigned int u; } v; v.f = f;
  unsigned int r = v.u + 0x7FFFu + ((v.u >> 16) & 1u);
  return (unsigned short)(r >> 16);
}

// global -> LDS direct copy, 16B per lane; lds dst is wave-uniform base (+lane*16 by HW)
__device__ __forceinline__ void gload_lds16(const void* g, void* l) {
  __builtin_amdgcn_global_load_lds(
      (const __attribute__((address_space(1))) void*)g,
      (__attribute__((address_space(3))) void*)l, 16, 0, 0);
}

// ---------- prep: conv (blocks 0..4095) + weight cvt (blocks 4096..8191) ----------
__global__ __launch_bounds__(256)
void prep_kernel(const float* __restrict__ x,
                 const float* __restrict__ wq3, const float* __restrict__ bq3,
                 const float* __restrict__ wk3, const float* __restrict__ bk3,
                 const float* __restrict__ wv3, const float* __restrict__ bv3,
                 unsigned short* __restrict__ cq, unsigned short* __restrict__ ck,
                 unsigned short* __restrict__ cv,
                 const float* __restrict__ wq, const float* __restrict__ wk,
                 const float* __restrict__ wv, const float* __restrict__ wo,
                 unsigned short* __restrict__ wqb, unsigned short* __restrict__ wkb,
                 unsigned short* __restrict__ wvb, unsigned short* __restrict__ wob)
{
  if (blockIdx.x >= 4096) {
    int bb = blockIdx.x - 4096;
    const float* src; unsigned short* dst;
    switch (bb >> 10) {
      case 0: src = wq; dst = wqb; break;
      case 1: src = wk; dst = wkb; break;
      case 2: src = wv; dst = wvb; break;
      default: src = wo; dst = wob; break;
    }
    int i = (bb & 1023) * 1024 + threadIdx.x * 4;
    f32x4 v = *(const f32x4*)(src + i);
    u16x4 o;
    #pragma unroll
    for (int j = 0; j < 4; j++) o[j] = f2bf(v[j]);
    *(u16x4*)(dst + i) = o;
    return;
  }
  int t = blockIdx.x;            // b*2048+s, 0..4095
  int s = t & 2047;
  int d0 = threadIdx.x * 4;
  int base = t * 1024 + d0;
  f32x4 xc = *(const f32x4*)(x + base);
  f32x4 xm = (s > 0)    ? *(const f32x4*)(x + base - 1024) : f32x4{0.f,0.f,0.f,0.f};
  f32x4 xp = (s < 2047) ? *(const f32x4*)(x + base + 1024) : f32x4{0.f,0.f,0.f,0.f};

  #pragma unroll
  for (int path = 0; path < 3; path++) {
    const float* wP = (path == 0) ? wq3 : ((path == 1) ? wk3 : wv3);
    const float* bP = (path == 0) ? bq3 : ((path == 1) ? bk3 : bv3);
    unsigned short* oP = (path == 0) ? cq : ((path == 1) ? ck : cv);
    f32x4 w0 = *(const f32x4*)(wP + d0*3);
    f32x4 w1 = *(const f32x4*)(wP + d0*3 + 4);
    f32x4 w2 = *(const f32x4*)(wP + d0*3 + 8);
    f32x4 b4 = *(const f32x4*)(bP + d0);
    u16x4 o;
    #pragma unroll
    for (int dd = 0; dd < 4; dd++) {
      float wa, wb, wc;
      int j0 = dd*3, j1 = dd*3+1, j2 = dd*3+2;
      wa = (j0 < 4) ? w0[j0] : ((j0 < 8) ? w1[j0-4] : w2[j0-8]);
      wb = (j1 < 4) ? w0[j1] : ((j1 < 8) ? w1[j1-4] : w2[j1-8]);
      wc = (j2 < 4) ? w0[j2] : ((j2 < 8) ? w1[j2-4] : w2[j2-8]);
      o[dd] = f2bf(xm[dd]*wa + xc[dd]*wb + xp[dd]*wc + b4[dd]);
    }
    *(u16x4*)(oP + base) = o;
  }
}

// ---------- q/k/v projections; BK=32, 3-buffer, counted vmcnt, 1 barrier/iter ----------
// q/k -> [B,H,S,64]; v -> tile-blocked [bh][S/64][64d][64k]
__global__ __launch_bounds__(256, 3)
void gemm_qkv_kernel(const unsigned short* __restrict__ cq, const unsigned short* __restrict__ ck,
                     const unsigned short* __restrict__ cv,
                     const unsigned short* __restrict__ wqb, const unsigned short* __restrict__ wkb,
                     const unsigned short* __restrict__ wvb,
                     const float* __restrict__ bq, const float* __restrict__ bk,
                     const float* __restrict__ bv,
                     unsigned short* __restrict__ qo, unsigned short* __restrict__ ko,
                     unsigned short* __restrict__ vtb)
{
  const int K = 1024;
  __shared__ alignas(16) unsigned short lA[3 * 4096];   // 128x32 per buf
  __shared__ alignas(16) unsigned short lB[3 * 4096];
  int z = blockIdx.z;
  const unsigned short* A = (z == 0) ? cq : ((z == 1) ? ck : cv);
  const unsigned short* W = (z == 0) ? wqb : ((z == 1) ? wkb : wvb);
  const float* bias       = (z == 0) ? bq : ((z == 1) ? bk : bv);
  // Q: fold 1/sqrt(64) AND log2(e) so attn can use exp2 with no per-element fixup
  float scale             = (z == 0) ? 0.125f * 1.4426950408889634f : 1.0f;

  int bm = blockIdx.y * 128, bn = blockIdx.x * 128;
  const int tid = threadIdx.x, lane = tid & 63, w = tid >> 6;
  const int lrow = lane & 15, lgrp = lane >> 4;
  const int wm = (w >> 1) * 64, wn = (w & 1) * 64;

  f32x4 acc[4][4];
  #pragma unroll
  for (int i = 0; i < 4; i++)
    #pragma unroll
    for (int j = 0; j < 4; j++) acc[i][j] = f32x4{0.f,0.f,0.f,0.f};

  // LDS[row][c] = global[row][c ^ (row&3)] (involution): linear dest, swizzled source
  auto STAGE = [&](int buf, int k0) {
    #pragma unroll
    for (int c = 0; c < 2; c++) {
      int slot_base = c * 256 + w * 64;          // wave-uniform
      int slot = slot_base + lane;
      int row = slot >> 2;
      int kc8 = ((slot & 3) ^ (row & 3)) << 3;
      gload_lds16(A + (size_t)(bm + row) * K + k0 + kc8, lA + buf * 4096 + slot_base * 8);
      gload_lds16(W + (size_t)(bn + row) * K + k0 + kc8, lB + buf * 4096 + slot_base * 8);
    }
  };

  STAGE(0, 0);
  STAGE(1, 32);
  int cur = 0, stg = 2;

  for (int t = 0; t < 32; t++) {
    if (t < 31) { asm volatile("s_waitcnt vmcnt(4)" ::: "memory"); }
    else        { asm volatile("s_waitcnt vmcnt(0)" ::: "memory"); }
    __builtin_amdgcn_s_barrier();
    __builtin_amdgcn_sched_barrier(0);
    if (t + 2 < 32) STAGE(stg, (t + 2) * 32);

    bf16x8 af[4], bfr[4];
    #pragma unroll
    for (int mt = 0; mt < 4; mt++) {
      int rr = wm + mt*16 + lrow;
      af[mt] = *(const bf16x8*)(lA + cur*4096 + (rr << 5) + ((lgrp ^ (rr & 3)) << 3));
    }
    #pragma unroll
    for (int nt = 0; nt < 4; nt++) {
      int rr = wn + nt*16 + lrow;
      bfr[nt] = *(const bf16x8*)(lB + cur*4096 + (rr << 5) + ((lgrp ^ (rr & 3)) << 3));
    }
    #pragma unroll
    for (int mt = 0; mt < 4; mt++)
      #pragma unroll
      for (int nt = 0; nt < 4; nt++)
        acc[mt][nt] = __builtin_amdgcn_mfma_f32_16x16x32_bf16(af[mt], bfr[nt], acc[mt][nt], 0, 0, 0);

    cur = (cur == 2) ? 0 : cur + 1;
    stg = (stg == 2) ? 0 : stg + 1;
  }

  if (z == 2) {
    // V: write transposed tile-blocked [tile][64d][64k]; i=0..3 consecutive s -> inner k
    #pragma unroll
    for (int mt = 0; mt < 4; mt++) {
      #pragma unroll
      for (int nt = 0; nt < 4; nt++) {
        int gn = bn + wn + nt*16 + lrow;
        float bb = bias[gn];
        int h = gn >> 6, dk = gn & 63;
        int gm0 = bm + wm + mt*16 + lgrp*4;
        int b = gm0 >> 11, s0 = gm0 & 2047;
        u16x4 pk;
        #pragma unroll
        for (int i = 0; i < 4; i++) pk[i] = f2bf(acc[mt][nt][i] + bb);
        unsigned short* dst = vtb +
            ((((size_t)(b*16 + h)) * 32 + (s0 >> 6)) * 64 + dk) * 64 + (s0 & 63);
        *(u16x4*)dst = pk;
      }
    }
  } else {
    unsigned short* O = (z == 0) ? qo : ko;
    #pragma unroll
    for (int mt = 0; mt < 4; mt++) {
      #pragma unroll
      for (int nt = 0; nt < 4; nt++) {
        int gn = bn + wn + nt*16 + lrow;
        float bb = bias[gn];
        int h = gn >> 6, dk = gn & 63;
        #pragma unroll
        for (int i = 0; i < 4; i++) {
          int gm = bm + wm + mt*16 + lgrp*4 + i;     // b*2048+s
          int b = gm >> 11, s = gm & 2047;
          float val = (acc[mt][nt][i] + bb) * scale;
          O[((size_t)(b*16 + h) * 2048 + s) * 64 + dk] = f2bf(val);
        }
      }
    }
  }
}

// ---------- final projection: f32 out; 64x128 tiles, BK=32, 3-buffer counted ----------
__global__ __launch_bounds__(256)
void gemm_out_kernel(const unsigned short* __restrict__ A, const unsigned short* __restrict__ W,
                     const float* __restrict__ bias, float* __restrict__ Out)
{
  const int K = 1024;
  __shared__ alignas(16) unsigned short lA[3 * 2048];   // 64x32 per buf
  __shared__ alignas(16) unsigned short lB[3 * 4096];   // 128x32 per buf
  int bm = blockIdx.y * 64, bn = blockIdx.x * 128;
  const int tid = threadIdx.x, lane = tid & 63, w = tid >> 6;
  const int lrow = lane & 15, lgrp = lane >> 4;
  const int wm = (w >> 1) * 32, wn = (w & 1) * 64;

  f32x4 acc[2][4];
  #pragma unroll
  for (int mt = 0; mt < 2; mt++)
    #pragma unroll
    for (int nt = 0; nt < 4; nt++) acc[mt][nt] = f32x4{0.f,0.f,0.f,0.f};

  auto STAGE = [&](int buf, int k0) {
    {
      int slot = tid;                          // 256 slots for A
      int row = slot >> 2;
      int kc8 = ((slot & 3) ^ (row & 3)) << 3;
      gload_lds16(A + (size_t)(bm + row) * K + k0 + kc8, lA + buf * 2048 + (w * 64) * 8);
    }
    #pragma unroll
    for (int c = 0; c < 2; c++) {
      int slot_base = c * 256 + w * 64;
      int slot = slot_base + lane;
      int row = slot >> 2;
      int kc8 = ((slot & 3) ^ (row & 3)) << 3;
      gload_lds16(W + (size_t)(bn + row) * K + k0 + kc8, lB + buf * 4096 + slot_base * 8);
    }
  };

  STAGE(0, 0);
  STAGE(1, 32);
  int cur = 0, stg = 2;

  for (int t = 0; t < 32; t++) {
    if (t < 31) { asm volatile("s_waitcnt vmcnt(3)" ::: "memory"); }
    else        { asm volatile("s_waitcnt vmcnt(0)" ::: "memory"); }
    __builtin_amdgcn_s_barrier();
    __builtin_amdgcn_sched_barrier(0);
    if (t + 2 < 32) STAGE(stg, (t + 2) * 32);

    bf16x8 af[2], bfr[4];
    #pragma unroll
    for (int mt = 0; mt < 2; mt++) {
      int rr = wm + mt*16 + lrow;
      af[mt] = *(const bf16x8*)(lA + cur*2048 + (rr << 5) + ((lgrp ^ (rr & 3)) << 3));
    }
    #pragma unroll
    for (int nt = 0; nt < 4; nt++) {
      int rr = wn + nt*16 + lrow;
      bfr[nt] = *(const bf16x8*)(lB + cur*4096 + (rr << 5) + ((lgrp ^ (rr & 3)) << 3));
    }
    #pragma unroll
    for (int mt = 0; mt < 2; mt++)
      #pragma unroll
      for (int nt = 0; nt < 4; nt++)
        acc[mt][nt] = __builtin_amdgcn_mfma_f32_16x16x32_bf16(af[mt], bfr[nt], acc[mt][nt], 0, 0, 0);

    cur = (cur == 2) ? 0 : cur + 1;
    stg = (stg == 2) ? 0 : stg + 1;
  }

  #pragma unroll
  for (int mt = 0; mt < 2; mt++) {
    #pragma unroll
    for (int nt = 0; nt < 4; nt++) {
      int gn = bn + wn + nt*16 + lrow;
      float bb = bias[gn];
      #pragma unroll
      for (int i = 0; i < 4; i++) {
        int gm = bm + wm + mt*16 + lgrp*4 + i;
        Out[(size_t)gm * 1024 + gn] = acc[mt][nt][i] + bb;
      }
    }
  }
}

// ---------- flash attention: swapped QK^T + in-reg P; 128-key double tiles (r17) ----------
// 4 waves x 32 q; grid 512. LDS 64KB: 2-buf x (16KB K + 16KB V), XOR-swizzled staging.
// NT=16 iterations of 128 keys. Softmax: P = exp2(s') (log2e folded into Q), l on VALU.
// P-packing: inline-asm v_cvt_pk_bf16_f32 (r18 A/B: native casts were -11%).
__global__ __launch_bounds__(256, 2)
void attn_kernel(const unsigned short* __restrict__ Q, const unsigned short* __restrict__ K,
                 const unsigned short* __restrict__ Vtb, unsigned short* __restrict__ O)
{
  const int S = 2048, NT = 16;          // 128-key tiles
  int n = blockIdx.x;
  int xcd = n & 7, r = n >> 3;          // r: 0..63
  int bh = (xcd << 2) | (r & 3);
  int qbase = (r >> 2) * 128;

  const int tid = threadIdx.x, lane = tid & 63, w = tid >> 6;   // 4 waves
  const int lq = lane & 31;             // q-col / key-row / d-row within 32
  const int lh = lane >> 5;             // half 0/1
  const unsigned short* Qh = Q   + (size_t)bh * S * 64;
  const unsigned short* Kh = K   + (size_t)bh * S * 64;
  const unsigned short* Vh = Vtb + (size_t)bh * 32 * 4096;   // [tile64][64d][64k], contiguous

  __shared__ alignas(16) unsigned short Kb[2][8192];   // 128 rows x 64, XOR swizzle
  __shared__ alignas(16) unsigned short Vb[2][8192];   // 2 consecutive vtb tiles

  bf16x8 qf[4];
  {
    const unsigned short* qp = Qh + (size_t)(qbase + w*32 + lq) * 64 + lh * 8;
    #pragma unroll
    for (int ks = 0; ks < 4; ks++)
      qf[ks] = *(const bf16x8*)(qp + ks * 16);
  }

  f32x16 oacc[2];
  #pragma unroll
  for (int i = 0; i < 16; i++) { oacc[0][i] = 0.f; oacc[1][i] = 0.f; }
  float lsum = 0.f;   // partial row-sum for q = qbase + w*32 + lq (this lane's half)

  // staging: 16KB per matrix = 1024 chunks; 256 thr -> 4 each (8 instr/wave total).
  // LDS[row][c] = global[row][c ^ (row&7)] (involution; linear dest, swizzled source)
  auto STAGE = [&](int buf, int gt) {
    const unsigned short* gK = Kh + (size_t)gt * 8192;
    const unsigned short* gV = Vh + (size_t)gt * 8192;   // vtb tiles 2gt,2gt+1 contiguous
    #pragma unroll
    for (int c = 0; c < 4; c++) {
      int slot_base = c * 256 + w * 64;          // wave-uniform
      int slot = slot_base + lane;
      int row = slot >> 3;                       // 0..127
      int srcoff = (row << 6) + (((slot & 7) ^ (row & 7)) << 3);
      gload_lds16(gK + srcoff, &Kb[buf][slot_base * 8]);
      gload_lds16(gV + srcoff, &Vb[buf][slot_base * 8]);
    }
  };

  STAGE(0, 0);
  int cur = 0;

  for (int t = 0; t < NT; t++) {
    asm volatile("s_waitcnt vmcnt(0)" ::: "memory");   // tile t landed (issued 1 iter ago)
    __builtin_amdgcn_s_barrier();
    __builtin_amdgcn_sched_barrier(0);
    if (t + 1 < NT) STAGE(cur ^ 1, t + 1);

    // ---- S^T = K Q^T : 16 MFMA over 4 key-subtiles of 32 ----
    f32x16 sacc[4];
    #pragma unroll
    for (int kt = 0; kt < 4; kt++)
      #pragma unroll
      for (int i = 0; i < 16; i++) sacc[kt][i] = 0.f;
    #pragma unroll
    for (int ks = 0; ks < 4; ks++) {
      #pragma unroll
      for (int kt = 0; kt < 4; kt++) {
        int row = kt*32 + lq;                     // key-row 0..127
        bf16x8 kf = *(const bf16x8*)(&Kb[cur][(row << 6) + ((((ks<<1)+lh) ^ (row & 7)) << 3)]);
        sacc[kt] = __builtin_amdgcn_mfma_f32_32x32x16_bf16(kf, qf[ks], sacc[kt], 0, 0, 0);
      }
    }

    // ---- P = exp2(s'); l-sum; cvt_pk + permlane32_swap -> 8 A-frags ----
    bf16x8 pa[8];
    #pragma unroll
    for (int kp = 0; kp < 8; kp++) {
      const int sv = kp >> 1;        // sacc subtile
      const int rb = (kp & 1) * 8;   // reg base
      float p[8];
      #pragma unroll
      for (int i = 0; i < 8; i++)
        p[i] = __builtin_amdgcn_exp2f(sacc[sv][rb + i]);
      lsum += ((p[0]+p[1]) + (p[2]+p[3])) + ((p[4]+p[5]) + (p[6]+p[7]));
      unsigned int X, Y, Z, W2;
      asm("v_cvt_pk_bf16_f32 %0, %1, %2" : "=v"(X)  : "v"(p[0]), "v"(p[1]));
      asm("v_cvt_pk_bf16_f32 %0, %1, %2" : "=v"(Y)  : "v"(p[2]), "v"(p[3]));
      asm("v_cvt_pk_bf16_f32 %0, %1, %2" : "=v"(Z)  : "v"(p[4]), "v"(p[5]));
      asm("v_cvt_pk_bf16_f32 %0, %1, %2" : "=v"(W2) : "v"(p[6]), "v"(p[7]));
      u32x2 rxz = __builtin_amdgcn_permlane32_swap(X, Z, false, false);
      u32x2 ryw = __builtin_amdgcn_permlane32_swap(Y, W2, false, false);
      union { unsigned int u[4]; bf16x8 v; } pk;
      pk.u[0] = rxz[0]; pk.u[1] = ryw[0]; pk.u[2] = rxz[1]; pk.u[3] = ryw[1];
      pa[kp] = pk.v;
    }

    // ---- O^T += (P V)^T : 16 MFMA; V rows 0..63 = keys 0..63, rows 64..127 = keys 64..127 ----
    __builtin_amdgcn_s_setprio(1);
    #pragma unroll
    for (int kp = 0; kp < 8; kp++) {
      int rbase = (kp >> 2) << 6;                 // 0 or 64 (which vtb tile)
      int ck = ((kp & 3) << 1) + lh;              // k-chunk within tile
      #pragma unroll
      for (int dt = 0; dt < 2; dt++) {
        int row = rbase + dt*32 + lq;
        bf16x8 vf = *(const bf16x8*)(&Vb[cur][(row << 6) + ((ck ^ (row & 7)) << 3)]);
        oacc[dt] = __builtin_amdgcn_mfma_f32_32x32x16_bf16(pa[kp], vf, oacc[dt], 0, 0, 0);
      }
    }
    __builtin_amdgcn_s_setprio(0);

    cur ^= 1;
  }

  // l(q): combine halves once (lane lq,lh held keys of its half for q = w*32+lq)
  float ltot = lsum + __shfl_xor(lsum, 32, 64);

  // epilogue: D layout col=lane&31 -> d, row=(reg&3)+8*(reg>>2)+4*lh -> q.
  int b = bh >> 4, h = bh & 15;
  #pragma unroll
  for (int reg = 0; reg < 16; reg++) {
    int qrl = (reg & 3) + 8*(reg >> 2) + 4*lh;     // 0..31
    float lq_ = __shfl(ltot, qrl, 64);
    float rl = 1.0f / lq_;
    int qrow = qbase + w*32 + qrl;
    unsigned short* dst = O + ((size_t)(b*2048 + qrow)) * 1024 + h*64 + lq;
    dst[0]  = f2bf(oacc[0][reg] * rl);
    dst[32] = f2bf(oacc[1][reg] * rl);
  }
}

// ---------- launcher ----------
extern "C" void kernel_launch(void* const* d_in, const int* in_sizes, int n_in,
                              void* d_out, int out_size, void* d_ws, size_t ws_size,
                              hipStream_t stream)
{
  const float* x     = (const float*)d_in[0];
  const float* dwq_w = (const float*)d_in[1];
  const float* dwq_b = (const float*)d_in[2];
  const float* dwk_w = (const float*)d_in[3];
  const float* dwk_b = (const float*)d_in[4];
  const float* dwv_w = (const float*)d_in[5];
  const float* dwv_b = (const float*)d_in[6];
  const float* wq    = (const float*)d_in[7];
  const float* bq    = (const float*)d_in[8];
  const float* wk    = (const float*)d_in[9];
  const float* bk    = (const float*)d_in[10];
  const float* wv    = (const float*)d_in[11];
  const float* bv    = (const float*)d_in[12];
  const float* wo    = (const float*)d_in[13];
  const float* bo    = (const float*)d_in[14];
  float* out = (float*)d_out;

  char* ws = (char*)d_ws;
  const size_t MB = 1024 * 1024;
  unsigned short* cq  = (unsigned short*)(ws + 0);        // 8MB (reused as attn_out)
  unsigned short* ck  = (unsigned short*)(ws + 8*MB);     // 8MB (reused as vtb)
  unsigned short* cv  = (unsigned short*)(ws + 16*MB);
  unsigned short* qd  = (unsigned short*)(ws + 24*MB);    // [B,H,S,64] bf16
  unsigned short* kd  = (unsigned short*)(ws + 32*MB);
  unsigned short* wqb = (unsigned short*)(ws + 48*MB);
  unsigned short* wkb = (unsigned short*)(ws + 50*MB);
  unsigned short* wvb = (unsigned short*)(ws + 52*MB);
  unsigned short* wob = (unsigned short*)(ws + 54*MB);
  unsigned short* attn_out = cq;                          // cq dead after gemm_qkv
  unsigned short* vtb      = ck;                          // ck dead after gemm_qkv

  prep_kernel<<<8192, 256, 0, stream>>>(x, dwq_w, dwq_b, dwk_w, dwk_b, dwv_w, dwv_b,
                                        cq, ck, cv, wq, wk, wv, wo, wqb, wkb, wvb, wob);
  gemm_qkv_kernel<<<dim3(8, 32, 3), 256, 0, stream>>>(cq, ck, cv, wqb, wkb, wvb, bq, bk, bv, qd, kd, vtb);
  attn_kernel<<<512, 256, 0, stream>>>(qd, kd, vtb, attn_out);
  gemm_out_kernel<<<dim3(8, 64), 256, 0, stream>>>(attn_out, wob, bo, out);
}